// Round 2
// baseline (2493.098 us; speedup 1.0000x reference)
//
#include <hip/hip_runtime.h>
#include <cstdint>
#include <cstddef>

// KAN layer: out[b,j] = sum_i ( w0(b,i)*C[j,i,lo(b,i)] + w1(b,i)*C[j,i,lo(b,i)+1] )
// where basis of clip(tanh(x)) is 2-sparse with adjacent nonzeros.
// lane = b, 64 j-accumulators per thread, v_dot2_f32_f16 inner op.

typedef _Float16 half2_v __attribute__((ext_vector_type(2)));
typedef __fp16  fp16x2  __attribute__((ext_vector_type(2)));

__device__ __forceinline__ half2_v u32_as_h2(uint32_t u) {
  union { uint32_t u; half2_v h; } c; c.u = u; return c.h;
}
__device__ __forceinline__ uint32_t h2_as_u32(half2_v h) {
  union { uint32_t u; half2_v h; } c; c.h = h; return c.u;
}
__device__ __forceinline__ half2_v cvt_pk_h2(float a, float b) {
  union { fp16x2 f; half2_v h; } c;
  c.f = __builtin_amdgcn_cvt_pkrtz(a, b);
  return c.h;
}

__device__ __forceinline__ float dot2f(half2_v a, half2_v b, float c) {
#if __has_builtin(__builtin_amdgcn_fdot2)
  return __builtin_amdgcn_fdot2(a, b, c, false);
#else
  return c + (float)a[0] * (float)b[0] + (float)a[1] * (float)b[1];
#endif
}

#define TI 8        // i's per LDS stage
#define BT 512      // b rows per block (8 waves, lane = b)
#define JT 64       // j columns per block (per-thread accumulators)
#define ISPL 8      // i-dimension splits (atomic accumulate)
#define IRANGE (1024 / ISPL)

__global__ __launch_bounds__(512)
void kan_main(const float* __restrict__ x, const float* __restrict__ coef,
              const float* __restrict__ knots, float* __restrict__ out) {
  // Plds[(i_loc*12+lo)*64 + slot*4 + sub]: f16x2 pairs (C[j,i,lo], C[j,i,lo+1]),
  // uint4 groups rotated by lo to kill the stride-64 bank conflict.
  __shared__ uint32_t Plds[TI * 12 * 64];   // 24 KB
  __shared__ float2 K2s[16];
  __shared__ float INVWs[16];

  const int t    = threadIdx.x;   // 0..511
  const int lane = t & 63;
  const int wv   = t >> 6;        // 0..7
  const int b    = blockIdx.x * BT + t;
  const int j0   = blockIdx.y * JT;
  const int ibeg = blockIdx.z * IRANGE;

  if (t < 15) {
    const float k0 = knots[t], k1 = knots[t + 1];
    K2s[t]   = make_float2(k0, k1);
    INVWs[t] = 1.0f / (k1 - k0 + 1e-8f);
  }

  float acc[JT];
#pragma unroll
  for (int q = 0; q < JT; ++q) acc[q] = 0.0f;

  const float* xrow = x + (size_t)b * 1024;

  for (int ic = 0; ic < IRANGE; ic += TI) {
    const int i0 = ibeg + ic;
    __syncthreads();   // previous chunk's readers done (also covers knot table on iter 0)

    // Stage TI*12*64 = 6144 f16 pairs: thread handles (i_loc=wv, lo=r, jj=lane).
#pragma unroll
    for (int r = 0; r < 12; ++r) {
      const int i  = i0 + wv;
      const int jj = lane;
      const float* cp = coef + ((size_t)(j0 + jj) * 1024 + i) * 13 + r;
      const float c0 = cp[0];
      const float c1 = cp[1];
      half2_v h;
      h[0] = (_Float16)c0;
      h[1] = (_Float16)c1;
      const int slot = ((jj >> 2) + r) & 15;   // rotate groups by lo
      Plds[(wv * 12 + r) * 64 + slot * 4 + (jj & 3)] = h2_as_u32(h);
    }

    // This lane's x values for the chunk (8 consecutive i, 32B aligned).
    float xr[TI];
    {
      const float4 xa = *(const float4*)(xrow + i0);
      const float4 xb = *(const float4*)(xrow + i0 + 4);
      xr[0] = xa.x; xr[1] = xa.y; xr[2] = xa.z; xr[3] = xa.w;
      xr[4] = xb.x; xr[5] = xb.y; xr[6] = xb.z; xr[7] = xb.w;
    }
    __syncthreads();

    const uint4* P4 = (const uint4*)Plds;
#pragma unroll
    for (int ii = 0; ii < TI; ++ii) {
      float xc = tanhf(xr[ii]);
      xc = fminf(fmaxf(xc, -1.0f), 1.0f);
      int m = (int)((xc + 1.0f) * 7.5f);   // interval index; continuity makes +-1 ULP safe
      m = min(max(m, 0), 14);
      const float2 kk  = K2s[m];
      const float  inv = INVWs[m];
      const float  up  = (xc - kk.x) * inv;
      const float  dn  = (kk.y - xc) * inv;
      // pair = (C[.,lo], C[.,lo+1]) with lo = clamp(m-1,0,11):
      //  m==0      : up on c[0],  nothing on c[1]
      //  1<=m<=11  : dn on c[m-1], up on c[m]
      //  m==12     : dn on c[11], nothing (k=12 is the zero-pad column)
      //  m>=13     : zero
      const float w0 = (m == 0) ? up : ((m <= 12) ? dn : 0.0f);
      const float w1 = (m >= 1 && m <= 11) ? up : 0.0f;
      const half2_v hw = cvt_pk_h2(w0, w1);
      const int lo   = min(max(m - 1, 0), 11);
      const int base = (ii * 12 + lo) * 16;
#pragma unroll
      for (int g = 0; g < 16; ++g) {
        const uint4 v = P4[base + ((g + lo) & 15)];
        acc[4 * g + 0] = dot2f(hw, u32_as_h2(v.x), acc[4 * g + 0]);
        acc[4 * g + 1] = dot2f(hw, u32_as_h2(v.y), acc[4 * g + 1]);
        acc[4 * g + 2] = dot2f(hw, u32_as_h2(v.z), acc[4 * g + 2]);
        acc[4 * g + 3] = dot2f(hw, u32_as_h2(v.w), acc[4 * g + 3]);
      }
    }
  }

  float* orow = out + (size_t)b * 256 + j0;
#pragma unroll
  for (int q = 0; q < JT; ++q) atomicAdd(orow + q, acc[q]);
}

extern "C" void kernel_launch(void* const* d_in, const int* in_sizes, int n_in,
                              void* d_out, int out_size, void* d_ws, size_t ws_size,
                              hipStream_t stream) {
  const float* x     = (const float*)d_in[0];
  const float* coef  = (const float*)d_in[1];
  const float* knots = (const float*)d_in[2];
  float* out = (float*)d_out;

  (void)hipMemsetAsync(out, 0, (size_t)out_size * sizeof(float), stream);

  dim3 grid(8192 / BT, 256 / JT, ISPL);   // (16, 4, 8)
  kan_main<<<grid, 512, 0, stream>>>(x, coef, knots, out);
}

// Round 3
// 2077.636 us; speedup vs baseline: 1.2000x; 1.2000x over previous
//
#include <hip/hip_runtime.h>
#include <cstdint>
#include <cstddef>

// KAN layer: out[b,j] = sum_i ( w0(b,i)*C[j,i,lo(b,i)] + w1(b,i)*C[j,i,lo(b,i)+1] )
// basis of clip(tanh(x)) is 2-sparse with adjacent nonzeros.
// lane = b, 32 j-accumulators per thread (spill-free), v_dot2_f32_f16 inner op.

typedef _Float16 half2_v __attribute__((ext_vector_type(2)));
typedef __fp16  fp16x2  __attribute__((ext_vector_type(2)));

__device__ __forceinline__ half2_v u32_as_h2(uint32_t u) {
  union { uint32_t u; half2_v h; } c; c.u = u; return c.h;
}
__device__ __forceinline__ uint32_t h2_as_u32(half2_v h) {
  union { uint32_t u; half2_v h; } c; c.h = h; return c.u;
}
__device__ __forceinline__ half2_v cvt_pk_h2(float a, float b) {
  union { fp16x2 f; half2_v h; } c;
  c.f = __builtin_amdgcn_cvt_pkrtz(a, b);
  return c.h;
}

__device__ __forceinline__ float dot2f(half2_v a, half2_v b, float c) {
#if __has_builtin(__builtin_amdgcn_fdot2)
  return __builtin_amdgcn_fdot2(a, b, c, false);
#else
  return c + (float)a[0] * (float)b[0] + (float)a[1] * (float)b[1];
#endif
}

#define TI 8        // i's per LDS stage
#define BT 512      // b rows per block (8 waves, lane = b)
#define JT 32       // j columns per block (per-thread accumulators)
#define ISPL 4      // i-dimension splits (atomic accumulate)
#define IRANGE (1024 / ISPL)

__global__ __launch_bounds__(512, 4)
void kan_main(const float* __restrict__ x, const float* __restrict__ coef,
              const float* __restrict__ knots, float* __restrict__ out) {
  // Plds[(i_loc*12+lo)*32 + slot*4 + sub]: f16x2 pairs (C[j,i,lo], C[j,i,lo+1]).
  // uint4 groups (4 j's) rotated by lo: slot = ((jj>>2)+lo)&7. Row stride 128 B
  // is bank-transparent; conflicts only for lo1==lo2 (mod 8) -> <=2-way (free).
  __shared__ uint32_t Plds[TI * 12 * JT];   // 12 KB
  __shared__ float2 K2s[16];
  __shared__ float INVWs[16];

  const int t    = threadIdx.x;   // 0..511
  const int b    = blockIdx.x * BT + t;
  const int j0   = blockIdx.y * JT;
  const int ibeg = blockIdx.z * IRANGE;

  if (t < 15) {
    const float k0 = knots[t], k1 = knots[t + 1];
    K2s[t]   = make_float2(k0, k1);
    INVWs[t] = 1.0f / (k1 - k0 + 1e-8f);
  }

  float acc[JT];
#pragma unroll
  for (int q = 0; q < JT; ++q) acc[q] = 0.0f;

  const float* xrow = x + (size_t)b * 1024;

  // staging decomposition: thread t -> (jj, i_loc, half); covers 6 r's each.
  const int s_jj   = t & 31;
  const int s_iloc = (t >> 5) & 7;
  const int s_half = t >> 8;            // 0 or 1
  const int s_rbase = s_half * 6;

  for (int ic = 0; ic < IRANGE; ic += TI) {
    const int i0 = ibeg + ic;
    __syncthreads();   // previous chunk's readers done (covers knot table on iter 0)

    // Stage TI*12*32 = 3072 f16 pairs. Each thread: 6 consecutive r's for its
    // (i_loc, jj) -> reads walk a 48-B window of one cacheline.
    {
      const float* cp0 = coef + ((size_t)(j0 + s_jj) * 1024 + (i0 + s_iloc)) * 13 + s_rbase;
#pragma unroll
      for (int s = 0; s < 6; ++s) {
        const int r = s_rbase + s;
        const float c0 = cp0[s];
        const float c1 = cp0[s + 1];
        half2_v h;
        h[0] = (_Float16)c0;
        h[1] = (_Float16)c1;
        const int slot = ((s_jj >> 2) + r) & 7;
        Plds[(s_iloc * 12 + r) * 32 + slot * 4 + (s_jj & 3)] = h2_as_u32(h);
      }
    }

    // This lane's x values for the chunk (8 consecutive i, 32B aligned).
    float xr[TI];
    {
      const float4 xa = *(const float4*)(xrow + i0);
      const float4 xb = *(const float4*)(xrow + i0 + 4);
      xr[0] = xa.x; xr[1] = xa.y; xr[2] = xa.z; xr[3] = xa.w;
      xr[4] = xb.x; xr[5] = xb.y; xr[6] = xb.z; xr[7] = xb.w;
    }
    __syncthreads();

    const uint4* P4 = (const uint4*)Plds;
#pragma unroll
    for (int ii = 0; ii < TI; ++ii) {
      float xc = tanhf(xr[ii]);
      xc = fminf(fmaxf(xc, -1.0f), 1.0f);
      int m = (int)((xc + 1.0f) * 7.5f);   // interval index; continuity makes +-1 ULP safe
      m = min(max(m, 0), 14);
      const float2 kk  = K2s[m];
      const float  inv = INVWs[m];
      const float  up  = (xc - kk.x) * inv;
      const float  dn  = (kk.y - xc) * inv;
      //  m==0      : up on c[0]
      //  1<=m<=11  : dn on c[m-1], up on c[m]
      //  m==12     : dn on c[11]  (k=12 is the zero-pad column)
      //  m>=13     : zero
      const float w0 = (m == 0) ? up : ((m <= 12) ? dn : 0.0f);
      const float w1 = (m >= 1 && m <= 11) ? up : 0.0f;
      const half2_v hw = cvt_pk_h2(w0, w1);
      const int lo   = min(max(m - 1, 0), 11);
      const int base = (ii * 12 + lo) * 8;
#pragma unroll
      for (int g = 0; g < 8; ++g) {
        const uint4 v = P4[base + ((g + lo) & 7)];
        acc[4 * g + 0] = dot2f(hw, u32_as_h2(v.x), acc[4 * g + 0]);
        acc[4 * g + 1] = dot2f(hw, u32_as_h2(v.y), acc[4 * g + 1]);
        acc[4 * g + 2] = dot2f(hw, u32_as_h2(v.z), acc[4 * g + 2]);
        acc[4 * g + 3] = dot2f(hw, u32_as_h2(v.w), acc[4 * g + 3]);
      }
    }
  }

  float* orow = out + (size_t)b * 256 + j0;
#pragma unroll
  for (int q = 0; q < JT; ++q) atomicAdd(orow + q, acc[q]);
}

extern "C" void kernel_launch(void* const* d_in, const int* in_sizes, int n_in,
                              void* d_out, int out_size, void* d_ws, size_t ws_size,
                              hipStream_t stream) {
  const float* x     = (const float*)d_in[0];
  const float* coef  = (const float*)d_in[1];
  const float* knots = (const float*)d_in[2];
  float* out = (float*)d_out;

  (void)hipMemsetAsync(out, 0, (size_t)out_size * sizeof(float), stream);

  dim3 grid(8192 / BT, 256 / JT, ISPL);   // (16, 8, 4) = 512 blocks = 2/CU
  kan_main<<<grid, 512, 0, stream>>>(x, coef, knots, out);
}

// Round 4
// 498.535 us; speedup vs baseline: 5.0009x; 4.1675x over previous
//
#include <hip/hip_runtime.h>
#include <cstdint>
#include <cstddef>

// KAN layer: out[b,j] = sum_i ( w0(b,i)*C[j,i,lo(b,i)] + w1(b,i)*C[j,i,lo(b,i)+1] )
// basis of clip(tanh(x)) is 2-sparse with adjacent nonzeros.
// Prep kernel precomputes packed f16 (w0,w1) + lo per (b,i) into d_ws (chunk-major,
// coalesced). Main: lane = b, 32 j-accumulators, v_dot2_f32_f16 inner op.

typedef _Float16 half2_v __attribute__((ext_vector_type(2)));
typedef __fp16  fp16x2  __attribute__((ext_vector_type(2)));

__device__ __forceinline__ half2_v u32_as_h2(uint32_t u) {
  union { uint32_t u; half2_v h; } c; c.u = u; return c.h;
}
__device__ __forceinline__ uint32_t h2_as_u32(half2_v h) {
  union { uint32_t u; half2_v h; } c; c.h = h; return c.u;
}
__device__ __forceinline__ half2_v cvt_pk_h2(float a, float b) {
  union { fp16x2 f; half2_v h; } c;
  c.f = __builtin_amdgcn_cvt_pkrtz(a, b);
  return c.h;
}
__device__ __forceinline__ float dot2f(half2_v a, half2_v b, float c) {
#if __has_builtin(__builtin_amdgcn_fdot2)
  return __builtin_amdgcn_fdot2(a, b, c, false);
#else
  return c + (float)a[0] * (float)b[0] + (float)a[1] * (float)b[1];
#endif
}

#define TI 8        // i's per LDS stage (one chunk)
#define BT 256      // b rows per block (4 waves, lane = b)
#define JT 32       // j columns per block (per-thread accumulators)
#define ISPL 2      // i-dimension splits (atomic accumulate)
#define IRANGE (1024 / ISPL)
#define NCHUNK (1024 / TI)          // 128 chunks total
#define CH_STRIDE (8192 * TI)       // per-chunk elements in W/LO (chunk-major)

// ---- weight computation shared by prep and fallback ----
__device__ __forceinline__ void kan_weights(float xin, const float* __restrict__ knots,
                                            float& w0, float& w1, int& lo) {
  float xc = tanhf(xin);
  xc = fminf(fmaxf(xc, -1.0f), 1.0f);
  int m = (int)((xc + 1.0f) * 7.5f);   // interval index; continuity makes +-1 ULP safe
  m = min(max(m, 0), 14);
  const float k0 = knots[m], k1 = knots[m + 1];
  const float inv = 1.0f / (k1 - k0 + 1e-8f);
  const float up = (xc - k0) * inv;
  const float dn = (k1 - xc) * inv;
  //  m==0: up on c[0] | 1<=m<=11: dn on c[m-1], up on c[m] | m==12: dn on c[11] | m>=13: 0
  w0 = (m == 0) ? up : ((m <= 12) ? dn : 0.0f);
  w1 = (m >= 1 && m <= 11) ? up : 0.0f;
  lo = min(max(m - 1, 0), 11);
}

__global__ __launch_bounds__(256)
void kan_prep(const float* __restrict__ x, const float* __restrict__ knots,
              uint32_t* __restrict__ W2, uint8_t* __restrict__ LO2) {
  const int tid = blockIdx.x * 256 + threadIdx.x;   // 8192*1024 threads
  const int b = tid >> 10;
  const int i = tid & 1023;
  float w0, w1; int lo;
  kan_weights(x[(size_t)b * 1024 + i], knots, w0, w1, lo);
  const int idx = (i >> 3) * CH_STRIDE + b * TI + (i & 7);
  W2[idx] = h2_as_u32(cvt_pk_h2(w0, w1));
  LO2[idx] = (uint8_t)lo;
}

template <bool USE_PREP>
__global__ __launch_bounds__(256)
void kan_main(const float* __restrict__ x, const float* __restrict__ coef,
              const float* __restrict__ knots,
              const uint32_t* __restrict__ W2, const uint8_t* __restrict__ LO2,
              float* __restrict__ out) {
  // Plds[(i_loc*12+lo)*32 + slot*4 + sub]: f16x2 pairs (C[j,i,lo], C[j,i,lo+1]).
  // uint4 groups (4 j's) rotated by lo: slot = ((jj>>2)+lo)&7.
  __shared__ uint32_t Plds[TI * 12 * JT];   // 12 KB

  const int t    = threadIdx.x;   // 0..255
  const int b    = blockIdx.x * BT + t;
  const int j0   = blockIdx.y * JT;
  const int cbeg = blockIdx.z * (IRANGE / TI);   // chunk index range

  float acc[JT];
#pragma unroll
  for (int q = 0; q < JT; ++q) acc[q] = 0.0f;

  // staging decomposition: thread t -> (jj, i_loc); covers all 12 r's.
  const int s_jj   = t & 31;
  const int s_iloc = t >> 5;   // 0..7

  for (int c = cbeg; c < cbeg + IRANGE / TI; ++c) {
    const int i0 = c * TI;
    __syncthreads();   // previous chunk's readers done

    // Stage TI*12*32 = 3072 f16 pairs. Each thread: 12 r's for its (i_loc, jj),
    // reading 13 consecutive floats (52 B).
    {
      const float* cp0 = coef + ((size_t)(j0 + s_jj) * 1024 + (i0 + s_iloc)) * 13;
      float cv[13];
#pragma unroll
      for (int s = 0; s < 13; ++s) cv[s] = cp0[s];
#pragma unroll
      for (int r = 0; r < 12; ++r) {
        half2_v h;
        h[0] = (_Float16)cv[r];
        h[1] = (_Float16)cv[r + 1];
        const int slot = ((s_jj >> 2) + r) & 7;
        Plds[(s_iloc * 12 + r) * 32 + slot * 4 + (s_jj & 3)] = h2_as_u32(h);
      }
    }

    // Per-lane weights for this chunk.
    uint32_t wr[TI];
    int lor[TI];
    if constexpr (USE_PREP) {
      const uint4* wp = (const uint4*)(W2 + (size_t)c * CH_STRIDE + b * TI);
      const uint4 wa = wp[0], wb = wp[1];
      wr[0] = wa.x; wr[1] = wa.y; wr[2] = wa.z; wr[3] = wa.w;
      wr[4] = wb.x; wr[5] = wb.y; wr[6] = wb.z; wr[7] = wb.w;
      const uint2 lb = *(const uint2*)(LO2 + (size_t)c * CH_STRIDE + b * TI);
#pragma unroll
      for (int q = 0; q < 4; ++q) { lor[q] = (lb.x >> (8 * q)) & 0xff; lor[4 + q] = (lb.y >> (8 * q)) & 0xff; }
    } else {
      const float* xrow = x + (size_t)b * 1024 + i0;
      const float4 xa = *(const float4*)(xrow);
      const float4 xb = *(const float4*)(xrow + 4);
      const float xv[TI] = {xa.x, xa.y, xa.z, xa.w, xb.x, xb.y, xb.z, xb.w};
#pragma unroll
      for (int q = 0; q < TI; ++q) {
        float w0, w1; int lo;
        kan_weights(xv[q], knots, w0, w1, lo);
        wr[q] = h2_as_u32(cvt_pk_h2(w0, w1));
        lor[q] = lo;
      }
    }
    __syncthreads();

    const uint4* P4 = (const uint4*)Plds;
#pragma unroll
    for (int ii = 0; ii < TI; ++ii) {
      const half2_v hw = u32_as_h2(wr[ii]);
      const int lo = lor[ii];
      const int base = (ii * 12 + lo) * 8;
#pragma unroll
      for (int g = 0; g < 8; ++g) {
        const uint4 v = P4[base + ((g + lo) & 7)];
        acc[4 * g + 0] = dot2f(hw, u32_as_h2(v.x), acc[4 * g + 0]);
        acc[4 * g + 1] = dot2f(hw, u32_as_h2(v.y), acc[4 * g + 1]);
        acc[4 * g + 2] = dot2f(hw, u32_as_h2(v.z), acc[4 * g + 2]);
        acc[4 * g + 3] = dot2f(hw, u32_as_h2(v.w), acc[4 * g + 3]);
      }
    }
  }

  float* orow = out + (size_t)b * 256 + j0;
#pragma unroll
  for (int q = 0; q < JT; ++q) atomicAdd(orow + q, acc[q]);
}

extern "C" void kernel_launch(void* const* d_in, const int* in_sizes, int n_in,
                              void* d_out, int out_size, void* d_ws, size_t ws_size,
                              hipStream_t stream) {
  const float* x     = (const float*)d_in[0];
  const float* coef  = (const float*)d_in[1];
  const float* knots = (const float*)d_in[2];
  float* out = (float*)d_out;

  (void)hipMemsetAsync(out, 0, (size_t)out_size * sizeof(float), stream);

  const size_t nW = (size_t)8192 * 1024;           // one entry per (b,i)
  const size_t need = nW * 4 + nW;                 // W2 (u32) + LO2 (u8) = 42 MB
  dim3 grid(8192 / BT, 256 / JT, ISPL);            // (32, 8, 2) = 512 blocks

  if (ws_size >= need) {
    uint32_t* W2 = (uint32_t*)d_ws;
    uint8_t*  LO2 = (uint8_t*)(W2 + nW);
    kan_prep<<<(int)(nW / 256), 256, 0, stream>>>(x, knots, W2, LO2);
    kan_main<true><<<grid, BT, 0, stream>>>(x, coef, knots, W2, LO2, out);
  } else {
    kan_main<false><<<grid, BT, 0, stream>>>(x, coef, knots, nullptr, nullptr, out);
  }
}

// Round 5
// 277.032 us; speedup vs baseline: 8.9993x; 1.7996x over previous
//
#include <hip/hip_runtime.h>
#include <cstdint>
#include <cstddef>

// KAN layer: out[b,j] = sum_{i,k} basis_k(tanh x[b,i]) * C[j,i,k]
// basis is 2-sparse (adjacent lo, lo+1) and basis[...,12] == 0 always -> K=12/i.
// Fast path: materialize dense f16 A[b, i*12+k] (201 MB in d_ws) + f16 B[j, i*12+k],
// then m97-style MFMA GEMM (128x128 tile, BK=32, 16x16x32 f16, global_load_lds w=16,
// K-split 6 with fp32 atomic epilogue).
// Fallback (small ws): round-4 dot2 kernels (proven).

typedef _Float16 half2_v __attribute__((ext_vector_type(2)));
typedef __fp16  fp16x2  __attribute__((ext_vector_type(2)));
typedef _Float16 f16x8 __attribute__((ext_vector_type(8)));
typedef float f32x4 __attribute__((ext_vector_type(4)));

__device__ __forceinline__ half2_v u32_as_h2(uint32_t u) {
  union { uint32_t u; half2_v h; } c; c.u = u; return c.h;
}
__device__ __forceinline__ uint32_t h2_as_u32(half2_v h) {
  union { uint32_t u; half2_v h; } c; c.h = h; return c.u;
}
__device__ __forceinline__ half2_v cvt_pk_h2(float a, float b) {
  union { fp16x2 f; half2_v h; } c;
  c.f = __builtin_amdgcn_cvt_pkrtz(a, b);
  return c.h;
}
__device__ __forceinline__ float dot2f(half2_v a, half2_v b, float c) {
#if __has_builtin(__builtin_amdgcn_fdot2)
  return __builtin_amdgcn_fdot2(a, b, c, false);
#else
  return c + (float)a[0] * (float)b[0] + (float)a[1] * (float)b[1];
#endif
}
__device__ __forceinline__ uint16_t f16_bits(float v) {
  union { _Float16 h; uint16_t u; } c; c.h = (_Float16)v; return c.u;
}

// ---- shared basis-weight computation ----
__device__ __forceinline__ void kan_weights(float xin, const float* __restrict__ knots,
                                            float& w0, float& w1, int& lo) {
  float xc = tanhf(xin);
  xc = fminf(fmaxf(xc, -1.0f), 1.0f);
  int m = (int)((xc + 1.0f) * 7.5f);   // interval index; basis continuity makes +-1 ULP safe
  m = min(max(m, 0), 14);
  const float k0 = knots[m], k1 = knots[m + 1];
  const float inv = 1.0f / (k1 - k0 + 1e-8f);
  const float up = (xc - k0) * inv;
  const float dn = (k1 - xc) * inv;
  // m==0: up on basis[0] | 1<=m<=11: dn on basis[m-1], up on basis[m]
  // m==12: dn on basis[11] | m>=13: zero
  w0 = (m == 0) ? up : ((m <= 12) ? dn : 0.0f);
  w1 = (m >= 1 && m <= 11) ? up : 0.0f;
  lo = min(max(m - 1, 0), 11);
}

// ================= fast path: dense f16 GEMM =================
#define GM 8192
#define GN 256
#define GK 12288           // 1024 i * 12 k
#define KSPL 6
#define KPER (GK / KSPL)   // 2048

__global__ __launch_bounds__(256)
void kan_prep_A(const float* __restrict__ x, const float* __restrict__ knots,
                uint32_t* __restrict__ Aw) {   // Aw viewed as u32: 6 words per (b,i)
  const int tid = blockIdx.x * 256 + threadIdx.x;   // 8192*1024
  float w0, w1; int lo;
  kan_weights(x[tid], knots, w0, w1, lo);
  const uint32_t h0 = f16_bits(w0), h1 = f16_bits(w1);
  uint32_t wds[6];
#pragma unroll
  for (int wq = 0; wq < 6; ++wq) {
    const int ka = 2 * wq, kb = 2 * wq + 1;
    const uint32_t lo16 = (ka == lo) ? h0 : ((ka == lo + 1) ? h1 : 0u);
    const uint32_t hi16 = (kb == lo) ? h0 : ((kb == lo + 1) ? h1 : 0u);
    wds[wq] = lo16 | (hi16 << 16);
  }
  uint32_t* p = Aw + (size_t)tid * 6;
  *(uint2*)(p + 0) = make_uint2(wds[0], wds[1]);
  *(uint2*)(p + 2) = make_uint2(wds[2], wds[3]);
  *(uint2*)(p + 4) = make_uint2(wds[4], wds[5]);
}

__global__ __launch_bounds__(256)
void kan_prep_B(const float* __restrict__ coef, uint32_t* __restrict__ Bw) {
  const int tid = blockIdx.x * 256 + threadIdx.x;   // 256*1024 (j,i)
  const float* cp = coef + (size_t)tid * 13;
  uint32_t wds[6];
#pragma unroll
  for (int wq = 0; wq < 6; ++wq)
    wds[wq] = h2_as_u32(cvt_pk_h2(cp[2 * wq], cp[2 * wq + 1]));
  uint32_t* p = Bw + (size_t)tid * 6;
  *(uint2*)(p + 0) = make_uint2(wds[0], wds[1]);
  *(uint2*)(p + 2) = make_uint2(wds[2], wds[3]);
  *(uint2*)(p + 4) = make_uint2(wds[4], wds[5]);
}

__device__ __forceinline__ void load_lds16(const void* g, void* l) {
  __builtin_amdgcn_global_load_lds((const __attribute__((address_space(1))) void*)g,
                                   (__attribute__((address_space(3))) void*)l, 16, 0, 0);
}

__global__ __launch_bounds__(256)
void kan_gemm(const _Float16* __restrict__ A, const _Float16* __restrict__ B,
              float* __restrict__ out) {
  // A: [8192][12288] row-major f16. B: [256][12288] row-major f16 (i.e. B^T input).
  // out[m][n] += sum_k A[m][k]*B[n][k] over this block's K-slice.
  __shared__ __align__(16) char smem[16384];   // A-tile 8 KB | B-tile 8 KB
  char* As = smem;
  char* Bs = smem + 8192;

  const int t    = threadIdx.x;    // 0..255
  const int lane = t & 63;
  const int wv   = t >> 6;         // 0..3
  const int m0   = blockIdx.x * 128;
  const int n0   = blockIdx.y * 128;
  const int kbeg = blockIdx.z * KPER;

  const int mrow0 = (wv & 1) * 64;
  const int ncol0 = (wv >> 1) * 64;
  const int fr = lane & 15;        // fragment row/col
  const int fq = lane >> 4;        // quad

  f32x4 acc[4][4];
#pragma unroll
  for (int a = 0; a < 4; ++a)
#pragma unroll
    for (int b = 0; b < 4; ++b) acc[a][b] = (f32x4){0.f, 0.f, 0.f, 0.f};

  // staging: thread covers chunks {t, 256+t} of 512 16-B chunks per operand tile.
  // chunk -> row = chunk>>2, kc = chunk&3; LDS offset = chunk*16 (wave-uniform + lane*16).
  const int row_a0 = t >> 2, kc0 = t & 3;          // s=0 chunk = t
  const int row_a1 = (256 + t) >> 2;               // s=1 chunk = 256+t (same kc)

  for (int kt = 0; kt < KPER / 32; ++kt) {
    const int k0 = kbeg + kt * 32;
    const _Float16* Ab = A + (size_t)m0 * GK + k0 + kc0 * 8;
    const _Float16* Bb = B + (size_t)n0 * GK + k0 + kc0 * 8;
    load_lds16(Ab + (size_t)row_a0 * GK, As + t * 16);
    load_lds16(Ab + (size_t)row_a1 * GK, As + (256 + t) * 16);
    load_lds16(Bb + (size_t)row_a0 * GK, Bs + t * 16);
    load_lds16(Bb + (size_t)row_a1 * GK, Bs + (256 + t) * 16);
    __syncthreads();   // drains vmcnt (async LDS stores) before reads

    f16x8 af[4], bf[4];
#pragma unroll
    for (int mi = 0; mi < 4; ++mi)
      af[mi] = *(const f16x8*)(As + (mrow0 + mi * 16 + fr) * 64 + fq * 16);
#pragma unroll
    for (int ni = 0; ni < 4; ++ni)
      bf[ni] = *(const f16x8*)(Bs + (ncol0 + ni * 16 + fr) * 64 + fq * 16);

#pragma unroll
    for (int mi = 0; mi < 4; ++mi)
#pragma unroll
      for (int ni = 0; ni < 4; ++ni)
        acc[mi][ni] = __builtin_amdgcn_mfma_f32_16x16x32_f16(af[mi], bf[ni], acc[mi][ni], 0, 0, 0);

    __syncthreads();   // compute done before next stage overwrites
  }

#pragma unroll
  for (int mi = 0; mi < 4; ++mi) {
    const int gr = m0 + mrow0 + mi * 16 + fq * 4;
#pragma unroll
    for (int ni = 0; ni < 4; ++ni) {
      const int gc = n0 + ncol0 + ni * 16 + fr;
#pragma unroll
      for (int r = 0; r < 4; ++r)
        atomicAdd(&out[(size_t)(gr + r) * GN + gc], acc[mi][ni][r]);
    }
  }
}

// ================= fallback: round-4 dot2 path =================
#define TI 8
#define BT 256
#define JT 32
#define ISPL 2
#define IRANGE (1024 / ISPL)
#define CH_STRIDE (8192 * TI)

__global__ __launch_bounds__(256)
void kan_prep_dot2(const float* __restrict__ x, const float* __restrict__ knots,
                   uint32_t* __restrict__ W2, uint8_t* __restrict__ LO2) {
  const int tid = blockIdx.x * 256 + threadIdx.x;
  const int b = tid >> 10;
  const int i = tid & 1023;
  float w0, w1; int lo;
  kan_weights(x[(size_t)b * 1024 + i], knots, w0, w1, lo);
  const int idx = (i >> 3) * CH_STRIDE + b * TI + (i & 7);
  W2[idx] = h2_as_u32(cvt_pk_h2(w0, w1));
  LO2[idx] = (uint8_t)lo;
}

template <bool USE_PREP>
__global__ __launch_bounds__(256)
void kan_dot2(const float* __restrict__ x, const float* __restrict__ coef,
              const float* __restrict__ knots,
              const uint32_t* __restrict__ W2, const uint8_t* __restrict__ LO2,
              float* __restrict__ out) {
  __shared__ uint32_t Plds[TI * 12 * JT];
  const int t    = threadIdx.x;
  const int b    = blockIdx.x * BT + t;
  const int j0   = blockIdx.y * JT;
  const int cbeg = blockIdx.z * (IRANGE / TI);

  float acc[JT];
#pragma unroll
  for (int q = 0; q < JT; ++q) acc[q] = 0.0f;

  const int s_jj   = t & 31;
  const int s_iloc = t >> 5;

  for (int c = cbeg; c < cbeg + IRANGE / TI; ++c) {
    const int i0 = c * TI;
    __syncthreads();
    {
      const float* cp0 = coef + ((size_t)(j0 + s_jj) * 1024 + (i0 + s_iloc)) * 13;
      float cv[13];
#pragma unroll
      for (int s = 0; s < 13; ++s) cv[s] = cp0[s];
#pragma unroll
      for (int r = 0; r < 12; ++r) {
        half2_v h; h[0] = (_Float16)cv[r]; h[1] = (_Float16)cv[r + 1];
        const int slot = ((s_jj >> 2) + r) & 7;
        Plds[(s_iloc * 12 + r) * 32 + slot * 4 + (s_jj & 3)] = h2_as_u32(h);
      }
    }
    uint32_t wr[TI]; int lor[TI];
    if constexpr (USE_PREP) {
      const uint4* wp = (const uint4*)(W2 + (size_t)c * CH_STRIDE + b * TI);
      const uint4 wa = wp[0], wb = wp[1];
      wr[0] = wa.x; wr[1] = wa.y; wr[2] = wa.z; wr[3] = wa.w;
      wr[4] = wb.x; wr[5] = wb.y; wr[6] = wb.z; wr[7] = wb.w;
      const uint2 lb = *(const uint2*)(LO2 + (size_t)c * CH_STRIDE + b * TI);
#pragma unroll
      for (int q = 0; q < 4; ++q) { lor[q] = (lb.x >> (8 * q)) & 0xff; lor[4 + q] = (lb.y >> (8 * q)) & 0xff; }
    } else {
      const float* xrow = x + (size_t)b * 1024 + i0;
      const float4 xa = *(const float4*)(xrow);
      const float4 xb = *(const float4*)(xrow + 4);
      const float xv[TI] = {xa.x, xa.y, xa.z, xa.w, xb.x, xb.y, xb.z, xb.w};
#pragma unroll
      for (int q = 0; q < TI; ++q) {
        float w0, w1; int lo;
        kan_weights(xv[q], knots, w0, w1, lo);
        wr[q] = h2_as_u32(cvt_pk_h2(w0, w1));
        lor[q] = lo;
      }
    }
    __syncthreads();

    const uint4* P4 = (const uint4*)Plds;
#pragma unroll
    for (int ii = 0; ii < TI; ++ii) {
      const half2_v hw = u32_as_h2(wr[ii]);
      const int lo = lor[ii];
      const int base = (ii * 12 + lo) * 8;
#pragma unroll
      for (int g = 0; g < 8; ++g) {
        const uint4 v = P4[base + ((g + lo) & 7)];
        acc[4 * g + 0] = dot2f(hw, u32_as_h2(v.x), acc[4 * g + 0]);
        acc[4 * g + 1] = dot2f(hw, u32_as_h2(v.y), acc[4 * g + 1]);
        acc[4 * g + 2] = dot2f(hw, u32_as_h2(v.z), acc[4 * g + 2]);
        acc[4 * g + 3] = dot2f(hw, u32_as_h2(v.w), acc[4 * g + 3]);
      }
    }
  }

  float* orow = out + (size_t)b * 256 + j0;
#pragma unroll
  for (int q = 0; q < JT; ++q) atomicAdd(orow + q, acc[q]);
}

extern "C" void kernel_launch(void* const* d_in, const int* in_sizes, int n_in,
                              void* d_out, int out_size, void* d_ws, size_t ws_size,
                              hipStream_t stream) {
  const float* x     = (const float*)d_in[0];
  const float* coef  = (const float*)d_in[1];
  const float* knots = (const float*)d_in[2];
  float* out = (float*)d_out;

  (void)hipMemsetAsync(out, 0, (size_t)out_size * sizeof(float), stream);

  const size_t nA = (size_t)GM * GK;               // f16 elements
  const size_t nB = (size_t)GN * GK;
  const size_t needG = (nA + nB) * 2;              // ~208 MB
  const size_t nW = (size_t)8192 * 1024;
  const size_t needD = nW * 5;                     // 42 MB

  if (ws_size >= needG) {
    _Float16* Aw = (_Float16*)d_ws;
    _Float16* Bw = Aw + nA;
    kan_prep_A<<<(int)(nW / 256), 256, 0, stream>>>(x, knots, (uint32_t*)Aw);
    kan_prep_B<<<(int)(nB / 12 / 256), 256, 0, stream>>>(coef, (uint32_t*)Bw);
    dim3 grid(GM / 128, GN / 128, KSPL);           // (64, 2, 6) = 768 blocks
    kan_gemm<<<grid, 256, 0, stream>>>(Aw, Bw, out);
  } else if (ws_size >= needD) {
    uint32_t* W2 = (uint32_t*)d_ws;
    uint8_t*  LO2 = (uint8_t*)(W2 + nW);
    dim3 grid(8192 / BT, 256 / JT, ISPL);
    kan_prep_dot2<<<(int)(nW / 256), 256, 0, stream>>>(x, knots, W2, LO2);
    kan_dot2<true><<<grid, BT, 0, stream>>>(x, coef, knots, W2, LO2, out);
  } else {
    dim3 grid(8192 / BT, 256 / JT, ISPL);
    kan_dot2<false><<<grid, BT, 0, stream>>>(x, coef, knots, nullptr, nullptr, out);
  }
}